// Round 14
// baseline (449.086 us; speedup 1.0000x reference)
//
#include <hip/hip_runtime.h>
#include <hip/hip_bf16.h>

// ---------------------------------------------------------------------------
// S4D stack, MFMA everywhere, single in-place state buffer u (bf16 [H][M]):
// encoder GEMM(->u cm) -> 4x[ mats; fused SSM (u->LDS swz, state MFMA +
//   segmented LDS scan + Toeplitz conv MFMA -> ycm); GLU MFMA + LN (A and
//   residual staged from cm via pair-interleaved LDS; writes u in-place) ]
// -> decoder (reads u cm).
// glu LDS: dword[pos][130]: dword p of row pos = short2(ch 2p, ch 2p+1)
// ---------------------------------------------------------------------------

constexpr int B_ = 4, L_ = 8192, DIN = 64, H_ = 256, N2_ = 32, NL_ = 4, DOUT = 10;
constexpr int LC = 64, CHK = L_ / LC;     // 128 chunks/batch
constexpr int GCH = B_ * CHK;             // 512 global chunks
constexpr int M_ = B_ * L_;               // 32768 positions

// ws layout in float slots
constexpr size_t OFF_WOB  = 8388608;                   // bf16 Wo NL*512*256
constexpr size_t OFF_PW   = 8650752;                   // (legacy)
constexpr size_t OFF_PCT  = 8716288;                   // f32 Ct2 pairs
constexpr size_t OFF_PWLC = 8781824;                   // f32 w^64 pairs
constexpr size_t OFF_PZ   = 8847360;                   // f32 z=dtA pairs
constexpr size_t OFF_EWT  = 8912896;                   // f32 enc W^T
constexpr size_t OFF_UCM  = 8929280;                   // bf16 [H][M] u (in-place)
constexpr size_t OFF_YCM  = 13123584;                  // bf16 [H][M] y cm
constexpr size_t OFF_MT   = 21512192;                  // bf16 Ttr [H][64][64]
constexpr size_t OFF_MW   = 22036480;                  // bf16 Wtr
constexpr size_t OFF_MV   = 22560768;                  // bf16 Vtr
// end 23085056 slots = 92.3 MB

typedef short bf16x8 __attribute__((ext_vector_type(8)));
typedef short short8 __attribute__((ext_vector_type(8)));
typedef float f32x4  __attribute__((ext_vector_type(4)));
typedef int   int2v  __attribute__((ext_vector_type(2)));

__device__ __forceinline__ float b2f(short s) {
    union { float f; unsigned u; } c;
    c.u = ((unsigned)(unsigned short)s) << 16;
    return c.f;
}

// ---------------------------------------------------------------------------
__global__ __launch_bounds__(256) void k_params(
    const float* __restrict__ log_dt, const float* __restrict__ log_A_re,
    const float* __restrict__ A_im, const float* __restrict__ C_re,
    const float* __restrict__ C_im, float* __restrict__ ws)
{
    int idx = blockIdx.x * 256 + threadIdx.x;     // over NL*H*N2
    if (idx >= NL_ * H_ * N2_) return;
    int i  = idx / (H_ * N2_);
    int hh = (idx / N2_) % H_;
    float dt  = expf(log_dt[i * H_ + hh]);
    float Are = -expf(log_A_re[idx]);
    float Aim = A_im[idx];
    float zre = dt * Are, zim = dt * Aim;
    float er  = expf(zre);
    float wre = er * cosf(zim), wim = er * sinf(zim);
    float d   = Are * Are + Aim * Aim;
    float nre = wre - 1.f, nim = wim;
    float qre = (nre * Are + nim * Aim) / d;
    float qim = (nim * Are - nre * Aim) / d;
    float cr = C_re[idx], ci = C_im[idx];
    float ctre = cr * qre - ci * qim;
    float ctim = cr * qim + ci * qre;
    float er2 = expf(zre * (float)LC);
    float wlre = er2 * cosf(zim * (float)LC);
    float wlim = er2 * sinf(zim * (float)LC);
    ((float2*)(ws + OFF_PW))[idx]   = make_float2(wre, wim);
    ((float2*)(ws + OFF_PCT))[idx]  = make_float2(2.f * ctre, 2.f * ctim);
    ((float2*)(ws + OFF_PWLC))[idx] = make_float2(wlre, wlim);
    ((float2*)(ws + OFF_PZ))[idx]   = make_float2(zre, zim);
}

// ---------------------------------------------------------------------------
// per-channel bf16 matrices: Ttr[t][j]=k[t-j], Wtr[m][j], Vtr[t][m]
__global__ __launch_bounds__(256) void k_mats(const float* __restrict__ ws,
    int layer, __hip_bfloat16* __restrict__ mt, __hip_bfloat16* __restrict__ mw,
    __hip_bfloat16* __restrict__ mv)
{
    int h = blockIdx.x, tid = threadIdx.x;
    __shared__ float zre[32], zim[32], ctr[32], cti[32], kv[64];
    if (tid < 32) {
        float2 z = ((const float2*)(ws + OFF_PZ))[(size_t)layer*H_*N2_ + h*N2_ + tid];
        float2 c = ((const float2*)(ws + OFF_PCT))[(size_t)layer*H_*N2_ + h*N2_ + tid];
        zre[tid] = z.x; zim[tid] = z.y; ctr[tid] = c.x; cti[tid] = c.y;
    }
    __syncthreads();
    if (tid < 64) {
        float d = (float)tid, acc = 0.f;
        for (int n = 0; n < 32; n++) {
            float er = expf(zre[n] * d);
            float co = cosf(zim[n] * d), si = sinf(zim[n] * d);
            acc += er * (ctr[n] * co - cti[n] * si);
        }
        kv[tid] = acc;
    }
    __syncthreads();
    {   // Ttr
        int t = tid >> 2, j0 = (tid & 3) * 16;
        alignas(16) __hip_bfloat16 row[16];
        #pragma unroll
        for (int jj = 0; jj < 16; jj++) {
            int j = j0 + jj;
            row[jj] = __float2bfloat16(j <= t ? kv[t - j] : 0.f);
        }
        *(short8*)(mt + (size_t)h*4096 + t*64 + j0)     = *(short8*)&row[0];
        *(short8*)(mt + (size_t)h*4096 + t*64 + j0 + 8) = *(short8*)&row[8];
    }
    {   // Wtr
        int n = tid >> 3, j0 = (tid & 7) * 8;
        alignas(16) __hip_bfloat16 rre[8], rim[8];
        #pragma unroll
        for (int jj = 0; jj < 8; jj++) {
            float e = (float)(63 - (j0 + jj));
            float er = expf(zre[n] * e);
            rre[jj] = __float2bfloat16(er * cosf(zim[n] * e));
            rim[jj] = __float2bfloat16(er * sinf(zim[n] * e));
        }
        *(short8*)(mw + (size_t)h*4096 + (2*n)*64 + j0)   = *(short8*)&rre[0];
        *(short8*)(mw + (size_t)h*4096 + (2*n+1)*64 + j0) = *(short8*)&rim[0];
    }
    {   // Vtr
        int t = tid >> 2, n0 = (tid & 3) * 8;
        float e = (float)(t + 1);
        alignas(16) __hip_bfloat16 row[16];
        #pragma unroll
        for (int k = 0; k < 8; k++) {
            int n = n0 + k;
            float er = expf(zre[n] * e);
            float wr = er * cosf(zim[n] * e), wi = er * sinf(zim[n] * e);
            row[2*k]   = __float2bfloat16(ctr[n]*wr - cti[n]*wi);
            row[2*k+1] = __float2bfloat16(-(ctr[n]*wi + cti[n]*wr));
        }
        *(short8*)(mv + (size_t)h*4096 + t*64 + 2*n0)     = *(short8*)&row[0];
        *(short8*)(mv + (size_t)h*4096 + t*64 + 2*n0 + 8) = *(short8*)&row[8];
    }
}

// ---------------------------------------------------------------------------
__global__ __launch_bounds__(256) void k_transpose(const float* __restrict__ src,
    float* __restrict__ dst, int R, int Cc)
{
    __shared__ float t[32][33];
    int x = blockIdx.x * 32 + threadIdx.x;
    #pragma unroll
    for (int i = 0; i < 4; i++) {
        int yy = blockIdx.y * 32 + threadIdx.y + i * 8;
        if (x < Cc && yy < R) t[threadIdx.y + i * 8][threadIdx.x] = src[(size_t)yy * Cc + x];
    }
    __syncthreads();
    int xo = blockIdx.y * 32 + threadIdx.x;
    #pragma unroll
    for (int i = 0; i < 4; i++) {
        int yo = blockIdx.x * 32 + threadIdx.y + i * 8;
        if (xo < R && yo < Cc) dst[(size_t)yo * R + xo] = t[threadIdx.x][threadIdx.y + i * 8];
    }
}

// ---------------------------------------------------------------------------
__global__ __launch_bounds__(256) void k_wcvt(const float* __restrict__ src,
    __hip_bfloat16* __restrict__ dst, int n4)
{
    int i = blockIdx.x * 256 + threadIdx.x;
    if (i >= n4) return;
    float4 v = ((const float4*)src)[i];
    union { __hip_bfloat16 b[4]; uint2 u; } o;
    o.b[0] = __float2bfloat16(v.x); o.b[1] = __float2bfloat16(v.y);
    o.b[2] = __float2bfloat16(v.z); o.b[3] = __float2bfloat16(v.w);
    ((uint2*)dst)[i] = o.u;
}

// ---------------------------------------------------------------------------
// encoder: h = x @ encWT + b; writes u bf16 channel-major
__global__ __launch_bounds__(256) void k_encoder(const float* __restrict__ x,
    const float* __restrict__ encWT, const float* __restrict__ enc_b,
    __hip_bfloat16* __restrict__ u)
{
    __shared__ float As[DIN][36];
    __shared__ float Bs[32][268];          // B-tiles; later f32 stage [32 pos][256 ch]
    int m0e = blockIdx.x * 32;
    int tid = threadIdx.x;
    const float4* x4 = (const float4*)x;
    #pragma unroll
    for (int q = 0; q < 2; q++) {
        int f = tid * 2 + q;
        int row = f >> 4, kq = f & 15;
        float4 v = x4[(size_t)(m0e + row) * 16 + kq];
        As[kq * 4 + 0][row] = v.x; As[kq * 4 + 1][row] = v.y;
        As[kq * 4 + 2][row] = v.z; As[kq * 4 + 3][row] = v.w;
    }
    int tx = tid & 31, ty = tid >> 5;
    float acc[4][8];
    #pragma unroll
    for (int p = 0; p < 4; p++)
        #pragma unroll
        for (int j = 0; j < 8; j++) acc[p][j] = 0.f;
    const float4* w4 = (const float4*)encWT;
    for (int ks = 0; ks < 2; ks++) {
        __syncthreads();
        #pragma unroll
        for (int it = 0; it < 8; it++) {
            int q = it * 256 + tid;
            int row = q >> 6, c4 = q & 63;
            *(float4*)&Bs[row][c4 * 4] = w4[ks * 2048 + q];
        }
        __syncthreads();
        #pragma unroll 8
        for (int kk = 0; kk < 32; kk++) {
            int k = ks * 32 + kk;
            float4 a  = *(const float4*)&As[k][ty * 4];
            float4 b0 = *(const float4*)&Bs[kk][tx * 4];
            float4 b1 = *(const float4*)&Bs[kk][128 + tx * 4];
            float av[4] = {a.x, a.y, a.z, a.w};
            float bv[8] = {b0.x, b0.y, b0.z, b0.w, b1.x, b1.y, b1.z, b1.w};
            #pragma unroll
            for (int p = 0; p < 4; p++)
                #pragma unroll
                for (int j = 0; j < 8; j++)
                    acc[p][j] = fmaf(av[p], bv[j], acc[p][j]);
        }
    }
    float4 eb0 = *(const float4*)&enc_b[tx * 4];
    float4 eb1 = *(const float4*)&enc_b[128 + tx * 4];
    float ebv[8] = {eb0.x, eb0.y, eb0.z, eb0.w, eb1.x, eb1.y, eb1.z, eb1.w};
    __syncthreads();                       // Bs dead -> f32 stage st2[pl][ch]
    #pragma unroll
    for (int p = 0; p < 4; p++) {
        int pl = ty * 4 + p;
        #pragma unroll
        for (int j = 0; j < 4; j++) Bs[pl][tx * 4 + j]       = acc[p][j] + ebv[j];
        #pragma unroll
        for (int j = 0; j < 4; j++) Bs[pl][128 + tx * 4 + j] = acc[p][j + 4] + ebv[j + 4];
    }
    __syncthreads();
    // u write: thread = channel
    {
        alignas(16) __hip_bfloat16 row[32];
        #pragma unroll
        for (int pl = 0; pl < 32; pl++) row[pl] = __float2bfloat16(Bs[pl][tid]);
        #pragma unroll
        for (int q = 0; q < 4; q++)
            *(short8*)(u + (size_t)tid * M_ + m0e + q * 8) = *(short8*)&row[q * 8];
    }
}

// ---------------------------------------------------------------------------
// FUSED SSM: block = (channel, batch). u staged in XOR-swizzled LDS.
// Phase1: chunk-state MFMA -> swz LDS. Phase2: 8-way segmented scan. Phase3:
// conv MFMA + carry + GELU. swizzle: elem e of chunk c at c*64 + (e^((c&7)<<3))
__global__ __launch_bounds__(256) void k_ssm(const __hip_bfloat16* __restrict__ ucm,
    const __hip_bfloat16* __restrict__ mt, const __hip_bfloat16* __restrict__ mw,
    const __hip_bfloat16* __restrict__ mv, const float* __restrict__ ws, int layer,
    const float* __restrict__ Dp, __hip_bfloat16* __restrict__ ycm)
{
    __shared__ __hip_bfloat16 ulds[L_];       // 16 KB swizzled u
    __shared__ __hip_bfloat16 st[CHK * 64];   // 16 KB swizzled states
    __shared__ float segT[8][32][2];          // 2 KB segment totals
    int h = blockIdx.x >> 2, b = blockIdx.x & 3;
    int tid = threadIdx.x, w = tid >> 6, l = tid & 63, l15 = l & 15, l4 = l >> 4;
    const __hip_bfloat16* ub = ucm + (size_t)h * M_ + (size_t)b * L_;
    #pragma unroll
    for (int it = 0; it < 4; it++) {
        int e0 = it * 2048 + tid * 8;
        short8 v = *(const short8*)(ub + e0);
        int c = e0 >> 6, e = e0 & 63;
        *(short8*)&ulds[c * 64 + (e ^ ((c & 7) << 3))] = v;
    }
    __syncthreads();
    {
        const __hip_bfloat16* bbase = mw + (size_t)h * 4096 + l15 * 64 + l4 * 8;
        #pragma unroll
        for (int half = 0; half < 2; half++) {
            int g0 = (w + half * 4) * 16;
            int ca = g0 + l15;
            f32x4 acc[4];
            #pragma unroll
            for (int nj = 0; nj < 4; nj++) acc[nj] = (f32x4)0.f;
            #pragma unroll
            for (int ks = 0; ks < 2; ks++) {
                int e = l4 * 8 + ks * 32;
                bf16x8 a = *(const bf16x8*)&ulds[ca * 64 + (e ^ ((ca & 7) << 3))];
                #pragma unroll
                for (int nj = 0; nj < 4; nj++) {
                    bf16x8 bb = *(const bf16x8*)(bbase + nj * 16 * 64 + ks * 32);
                    acc[nj] = __builtin_amdgcn_mfma_f32_16x16x32_bf16(a, bb, acc[nj], 0, 0, 0);
                }
            }
            #pragma unroll
            for (int nj = 0; nj < 4; nj++)
                #pragma unroll
                for (int r = 0; r < 4; r++) {
                    int c = g0 + l4 * 4 + r, e = nj * 16 + l15;
                    st[c * 64 + (e ^ ((c & 7) << 3))] = __float2bfloat16(acc[nj][r]);
                }
        }
    }
    __syncthreads();
    {
        int s = tid >> 5, n = tid & 31;
        float2 wl = ((const float2*)(ws + OFF_PWLC))[(size_t)layer * H_ * N2_ + h * 32 + n];
        float tr = 0.f, ti = 0.f;
        for (int j = 0; j < 16; j++) {
            int c = s * 16 + j;
            __hip_bfloat162* p = (__hip_bfloat162*)&st[c * 64 + ((2 * n) ^ ((c & 7) << 3))];
            float2 v = __bfloat1622float2(*p);
            float nr = fmaf(wl.x, tr, v.x); nr = fmaf(-wl.y, ti, nr);
            float ni = fmaf(wl.x, ti, v.y); ni = fmaf(wl.y, tr, ni);
            tr = nr; ti = ni;
        }
        segT[s][n][0] = tr; segT[s][n][1] = ti;
        __syncthreads();
        float wr = wl.x, wi = wl.y;
        #pragma unroll
        for (int q = 0; q < 4; q++) {
            float nr = wr * wr - wi * wi, ni = 2.f * wr * wi;
            wr = nr; wi = ni;
        }
        float ar = 0.f, ai = 0.f;
        for (int t = 0; t < s; t++) {
            float Tx = segT[t][n][0], Ty = segT[t][n][1];
            float nr = fmaf(wr, ar, Tx); nr = fmaf(-wi, ai, nr);
            float ni = fmaf(wr, ai, Ty); ni = fmaf(wi, ar, ni);
            ar = nr; ai = ni;
        }
        for (int j = 0; j < 16; j++) {
            int c = s * 16 + j;
            __hip_bfloat162* p = (__hip_bfloat162*)&st[c * 64 + ((2 * n) ^ ((c & 7) << 3))];
            float2 v = __bfloat1622float2(*p);
            *p = __float22bfloat162_rn(make_float2(ar, ai));
            float nr = fmaf(wl.x, ar, v.x); nr = fmaf(-wl.y, ai, nr);
            float ni = fmaf(wl.x, ai, v.y); ni = fmaf(wl.y, ar, ni);
            ar = nr; ai = ni;
        }
    }
    __syncthreads();
    {
        const __hip_bfloat16* bt = mt + (size_t)h * 4096 + l15 * 64 + l4 * 8;
        const __hip_bfloat16* bv = mv + (size_t)h * 4096 + l15 * 64 + l4 * 8;
        float Dh = Dp[layer * H_ + h];
        __hip_bfloat16* yb = ycm + (size_t)h * M_ + (size_t)b * L_;
        #pragma unroll
        for (int half = 0; half < 2; half++) {
            int g0 = (w + half * 4) * 16;
            int ca = g0 + l15;
            f32x4 acc[4];
            #pragma unroll
            for (int nj = 0; nj < 4; nj++) acc[nj] = (f32x4)0.f;
            #pragma unroll
            for (int ks = 0; ks < 2; ks++) {
                int e = l4 * 8 + ks * 32;
                bf16x8 a = *(const bf16x8*)&ulds[ca * 64 + (e ^ ((ca & 7) << 3))];
                #pragma unroll
                for (int nj = 0; nj < 4; nj++) {
                    bf16x8 bb = *(const bf16x8*)(bt + nj * 16 * 64 + ks * 32);
                    acc[nj] = __builtin_amdgcn_mfma_f32_16x16x32_bf16(a, bb, acc[nj], 0, 0, 0);
                }
            }
            #pragma unroll
            for (int ks = 0; ks < 2; ks++) {
                int e = l4 * 8 + ks * 32;
                bf16x8 a = *(const bf16x8*)&st[ca * 64 + (e ^ ((ca & 7) << 3))];
                #pragma unroll
                for (int nj = 0; nj < 4; nj++) {
                    bf16x8 bb = *(const bf16x8*)(bv + nj * 16 * 64 + ks * 32);
                    acc[nj] = __builtin_amdgcn_mfma_f32_16x16x32_bf16(a, bb, acc[nj], 0, 0, 0);
                }
            }
            #pragma unroll
            for (int nj = 0; nj < 4; nj++)
                #pragma unroll
                for (int r = 0; r < 4; r++) {
                    int g = g0 + l4 * 4 + r;
                    int e = nj * 16 + l15;
                    float uv = __bfloat162float(ulds[g * 64 + (e ^ ((g & 7) << 3))]);
                    float v = fmaf(Dh, uv, acc[nj][r]);
                    float gg = 0.7978845608028654f * fmaf(0.044715f * v, v * v, v);
                    float yv = v / (1.f + __expf(-2.f * gg));
                    yb[(size_t)g * 64 + nj * 16 + l15] = __float2bfloat16(yv);
                }
        }
    }
}

// ---------------------------------------------------------------------------
// fused MFMA GLU+LN v11: BM=32, grid 1024. A AND residual staged from
// channel-major buffers into pair-interleaved pos-major LDS (dword[pos][130]);
// u updated in-place (own 32-pos slice only). lt aliases dead staging LDS.
__global__ __launch_bounds__(256) void k_glu_mfma(
    const __hip_bfloat16* __restrict__ ycm,  // [H][M] bf16 cm (A operand)
    const __hip_bfloat16* __restrict__ wob,  // [512,256] bf16
    const float* __restrict__ bo, const float* __restrict__ lnw,
    const float* __restrict__ lnb,
    __hip_bfloat16* __restrict__ u)          // [H][M] bf16 cm in/out (residual)
{
    __shared__ int buf[8320];                // bufA[4160] + bufR[4160]; lt alias
    __shared__ float red[4][32][2];
    int* bufA = buf;
    int* bufR = buf + 4160;
    int tid = threadIdx.x;
    int w = tid >> 6, l = tid & 63, l15 = l & 15, l4 = l >> 4;
    int m0 = blockIdx.x * 32;
    int nv = w * 64;

    // ---- stage A (ycm) and R (u): thread = (pair p, pos-half ph)
    {
        int p = tid & 127, ph = tid >> 7;
        const __hip_bfloat16* a0p = ycm + (size_t)(2 * p) * M_ + m0 + ph * 16;
        const __hip_bfloat16* a1p = a0p + M_;
        const __hip_bfloat16* r0p = u + (size_t)(2 * p) * M_ + m0 + ph * 16;
        const __hip_bfloat16* r1p = r0p + M_;
        short8 a0a = *(const short8*)(a0p);
        short8 a0b = *(const short8*)(a0p + 8);
        short8 a1a = *(const short8*)(a1p);
        short8 a1b = *(const short8*)(a1p + 8);
        short8 r0a = *(const short8*)(r0p);
        short8 r0b = *(const short8*)(r0p + 8);
        short8 r1a = *(const short8*)(r1p);
        short8 r1b = *(const short8*)(r1p + 8);
        int* da = bufA + ph * 16 * 130 + p;
        int* dr = bufR + ph * 16 * 130 + p;
        #pragma unroll
        for (int j = 0; j < 8; j++) {
            da[j * 130]       = ((int)(unsigned short)a0a[j]) | (((int)(unsigned short)a1a[j]) << 16);
            da[(8 + j) * 130] = ((int)(unsigned short)a0b[j]) | (((int)(unsigned short)a1b[j]) << 16);
            dr[j * 130]       = ((int)(unsigned short)r0a[j]) | (((int)(unsigned short)r1a[j]) << 16);
            dr[(8 + j) * 130] = ((int)(unsigned short)r0b[j]) | (((int)(unsigned short)r1b[j]) << 16);
        }
    }
    __syncthreads();

    f32x4 accv[2][4], accg[2][4];
    #pragma unroll
    for (int sub = 0; sub < 2; sub++)
        #pragma unroll
        for (int nj = 0; nj < 4; nj++) { accv[sub][nj] = (f32x4)0.f; accg[sub][nj] = (f32x4)0.f; }

    int abase0 = l15 * 130 + l4 * 4;         // dword base, a0 (pos l15)
    #pragma unroll 2
    for (int ks = 0; ks < 8; ks++) {
        int k0 = ks * 32 + l4 * 8;
        union { int2v d[2]; bf16x8 v; } a0u, a1u;
        a0u.d[0] = *(const int2v*)&bufA[abase0 + ks * 16];
        a0u.d[1] = *(const int2v*)&bufA[abase0 + ks * 16 + 2];
        a1u.d[0] = *(const int2v*)&bufA[abase0 + 16 * 130 + ks * 16];
        a1u.d[1] = *(const int2v*)&bufA[abase0 + 16 * 130 + ks * 16 + 2];
        bf16x8 a0 = a0u.v;
        bf16x8 a1 = a1u.v;
        #pragma unroll
        for (int nj = 0; nj < 4; nj++) {
            bf16x8 bv = *(const bf16x8*)(wob + (size_t)(nv + nj * 16 + l15) * H_ + k0);
            bf16x8 bg = *(const bf16x8*)(wob + (size_t)(256 + nv + nj * 16 + l15) * H_ + k0);
            accv[0][nj] = __builtin_amdgcn_mfma_f32_16x16x32_bf16(a0, bv, accv[0][nj], 0, 0, 0);
            accg[0][nj] = __builtin_amdgcn_mfma_f32_16x16x32_bf16(a0, bg, accg[0][nj], 0, 0, 0);
            accv[1][nj] = __builtin_amdgcn_mfma_f32_16x16x32_bf16(a1, bv, accv[1][nj], 0, 0, 0);
            accg[1][nj] = __builtin_amdgcn_mfma_f32_16x16x32_bf16(a1, bg, accg[1][nj], 0, 0, 0);
        }
    }

    float bov[4], bog[4], lw[4], lb[4];
    #pragma unroll
    for (int nj = 0; nj < 4; nj++) {
        int cn = nv + nj * 16 + l15;
        bov[nj] = bo[cn]; bog[nj] = bo[256 + cn];
        lw[nj] = lnw[cn]; lb[nj] = lnb[cn];
    }
    const short* bufRs = (const short*)bufR;
    #pragma unroll
    for (int sub = 0; sub < 2; sub++) {
        #pragma unroll
        for (int r = 0; r < 4; r++) {
            int lr = sub * 16 + l4 * 4 + r;
            float s = 0.f, ss = 0.f;
            #pragma unroll
            for (int nj = 0; nj < 4; nj++) {
                int cn = nv + nj * 16 + l15;
                float uv = accv[sub][nj][r] + bov[nj];
                float ug = accg[sub][nj][r] + bog[nj];
                float z = uv / (1.f + __expf(-ug));
                float v = z + b2f(bufRs[lr * 260 + cn]);
                accv[sub][nj][r] = v;
                s += v; ss += v * v;
            }
            #pragma unroll
            for (int off = 1; off < 16; off <<= 1) {
                s  += __shfl_xor(s, off);
                ss += __shfl_xor(ss, off);
            }
            if (l15 == 0) { red[w][lr][0] = s; red[w][lr][1] = ss; }
        }
    }
    __syncthreads();                 // staging buffers dead -> reuse buf as lt
    short* lt = (short*)buf;
    #pragma unroll
    for (int sub = 0; sub < 2; sub++) {
        #pragma unroll
        for (int r = 0; r < 4; r++) {
            int lr = sub * 16 + l4 * 4 + r;
            float s  = red[0][lr][0] + red[1][lr][0] + red[2][lr][0] + red[3][lr][0];
            float ss = red[0][lr][1] + red[1][lr][1] + red[2][lr][1] + red[3][lr][1];
            float mu = s * (1.f / 256.f);
            float var = ss * (1.f / 256.f) - mu * mu;
            float rstd = rsqrtf(var + 1e-5f);
            #pragma unroll
            for (int nj = 0; nj < 4; nj++) {
                int cn = nv + nj * 16 + l15;
                float val = (accv[sub][nj][r] - mu) * rstd * lw[nj] + lb[nj];
                __hip_bfloat16 bval = __float2bfloat16(val);
                lt[cn * 34 + lr] = *(short*)&bval;
            }
        }
    }
    __syncthreads();
    {   // u write: thread = channel, 32 positions (in-place, own slice only)
        #pragma unroll
        for (int q = 0; q < 4; q++)
            *(short8*)(u + (size_t)tid * M_ + m0 + q * 8)
                = *(short8*)&lt[tid * 34 + q * 8];
    }
}

// ---------------------------------------------------------------------------
// decoder: reads u (bf16 channel-major) via LDS transpose; 64-pos tiles
__global__ __launch_bounds__(256) void k_decoder(const __hip_bfloat16* __restrict__ u,
    const float* __restrict__ out_W, const float* __restrict__ out_b,
    float* __restrict__ out)
{
    __shared__ float hs[64][260];
    __shared__ float wl[10][260];
    int m0 = blockIdx.x * 64;
    int tid = threadIdx.x;
    {   // thread = channel: 64 positions, 128 B contiguous
        const __hip_bfloat16* src = u + (size_t)tid * M_ + m0;
        bf16x8 raw[8];
        #pragma unroll
        for (int q = 0; q < 8; q++) raw[q] = *(const bf16x8*)(src + q * 8);
        #pragma unroll
        for (int p = 0; p < 64; p++)
            hs[p][tid] = b2f(raw[p >> 3][p & 7]);
    }
    for (int q = tid; q < 640; q += 256) {
        int r = q / 64, k4 = q % 64;
        *(float4*)&wl[r][k4 * 4] = ((const float4*)out_W)[q];
    }
    __syncthreads();
    int slot = tid & 15;
    if (slot < DOUT) {
        #pragma unroll
        for (int pass = 0; pass < 4; pass++) {
            int pl = pass * 16 + (tid >> 4);
            float a0 = 0.f, a1 = 0.f, a2 = 0.f, a3 = 0.f;
            #pragma unroll 8
            for (int k = 0; k < 256; k += 4) {
                a0 = fmaf(hs[pl][k + 0], wl[slot][k + 0], a0);
                a1 = fmaf(hs[pl][k + 1], wl[slot][k + 1], a1);
                a2 = fmaf(hs[pl][k + 2], wl[slot][k + 2], a2);
                a3 = fmaf(hs[pl][k + 3], wl[slot][k + 3], a3);
            }
            out[(size_t)(m0 + pl) * DOUT + slot] = (a0 + a1) + (a2 + a3) + out_b[slot];
        }
    }
}

// ---------------------------------------------------------------------------
extern "C" void kernel_launch(void* const* d_in, const int* in_sizes, int n_in,
                              void* d_out, int out_size, void* d_ws, size_t ws_size,
                              hipStream_t stream)
{
    (void)in_sizes; (void)n_in; (void)out_size; (void)ws_size;
    const float* x        = (const float*)d_in[0];
    const float* enc_W    = (const float*)d_in[1];
    const float* enc_b    = (const float*)d_in[2];
    const float* log_dt   = (const float*)d_in[3];
    const float* log_A_re = (const float*)d_in[4];
    const float* A_im     = (const float*)d_in[5];
    const float* C_re     = (const float*)d_in[6];
    const float* C_im     = (const float*)d_in[7];
    const float* Dp       = (const float*)d_in[8];
    const float* Wo       = (const float*)d_in[9];
    const float* bo       = (const float*)d_in[10];
    const float* lnw      = (const float*)d_in[11];
    const float* lnb      = (const float*)d_in[12];
    const float* out_W    = (const float*)d_in[13];
    const float* out_b    = (const float*)d_in[14];
    float* ws = (float*)d_ws;
    __hip_bfloat16* u   = (__hip_bfloat16*)(ws + OFF_UCM);
    __hip_bfloat16* ycm = (__hip_bfloat16*)(ws + OFF_YCM);
    __hip_bfloat16* mt = (__hip_bfloat16*)(ws + OFF_MT);
    __hip_bfloat16* mw = (__hip_bfloat16*)(ws + OFF_MW);
    __hip_bfloat16* mv = (__hip_bfloat16*)(ws + OFF_MV);
    __hip_bfloat16* wob = (__hip_bfloat16*)(ws + OFF_WOB);

    k_params<<<NL_ * H_ * N2_ / 256, 256, 0, stream>>>(log_dt, log_A_re, A_im, C_re, C_im, ws);
    dim3 tb(32, 8);
    k_transpose<<<dim3(DIN / 32, H_ / 32), tb, 0, stream>>>(enc_W, ws + OFF_EWT, H_, DIN);
    k_wcvt<<<(NL_ * 2 * H_ * H_ / 4 + 255) / 256, 256, 0, stream>>>(Wo, wob, NL_ * 2 * H_ * H_ / 4);
    k_encoder<<<M_ / 32, 256, 0, stream>>>(x, ws + OFF_EWT, enc_b, u);
    for (int i = 0; i < NL_; i++) {
        k_mats<<<H_, 256, 0, stream>>>(ws, i, mt, mw, mv);
        k_ssm<<<H_ * B_, 256, 0, stream>>>(u, mt, mw, mv, ws, i, Dp, ycm);
        k_glu_mfma<<<M_ / 32, 256, 0, stream>>>(ycm,
            wob + (size_t)i * 2 * H_ * H_, bo + (size_t)i * 2 * H_,
            lnw + (size_t)i * H_, lnb + (size_t)i * H_, u);
    }
    k_decoder<<<M_ / 64, 256, 0, stream>>>(u, out_W, out_b, (float*)d_out);
}

// Round 15
// 418.837 us; speedup vs baseline: 1.0722x; 1.0722x over previous
//
#include <hip/hip_runtime.h>
#include <hip/hip_bf16.h>

// ---------------------------------------------------------------------------
// S4D stack, MFMA everywhere, single in-place state buffer u (bf16 [H][M]):
// encoder GEMM(->u cm) -> 4x[ mats; fused SSM (u->LDS swz, state MFMA +
//   segmented LDS scan + Toeplitz conv MFMA -> ycm); GLU MFMA + LN v12
//   (2-tile pipelined, A/R staged from cm via pair-interleaved LDS; writes u
//   in-place) ] -> decoder (pair-interleaved staging).
// glu LDS: dword[pos][130]: dword p of row pos = short2(ch 2p, ch 2p+1)
// ---------------------------------------------------------------------------

constexpr int B_ = 4, L_ = 8192, DIN = 64, H_ = 256, N2_ = 32, NL_ = 4, DOUT = 10;
constexpr int LC = 64, CHK = L_ / LC;     // 128 chunks/batch
constexpr int GCH = B_ * CHK;             // 512 global chunks
constexpr int M_ = B_ * L_;               // 32768 positions

// ws layout in float slots
constexpr size_t OFF_WOB  = 8388608;                   // bf16 Wo NL*512*256
constexpr size_t OFF_PW   = 8650752;                   // (legacy)
constexpr size_t OFF_PCT  = 8716288;                   // f32 Ct2 pairs
constexpr size_t OFF_PWLC = 8781824;                   // f32 w^64 pairs
constexpr size_t OFF_PZ   = 8847360;                   // f32 z=dtA pairs
constexpr size_t OFF_EWT  = 8912896;                   // f32 enc W^T
constexpr size_t OFF_UCM  = 8929280;                   // bf16 [H][M] u (in-place)
constexpr size_t OFF_YCM  = 13123584;                  // bf16 [H][M] y cm
constexpr size_t OFF_MT   = 21512192;                  // bf16 Ttr [H][64][64]
constexpr size_t OFF_MW   = 22036480;                  // bf16 Wtr
constexpr size_t OFF_MV   = 22560768;                  // bf16 Vtr
// end 23085056 slots = 92.3 MB

typedef short bf16x8 __attribute__((ext_vector_type(8)));
typedef short short8 __attribute__((ext_vector_type(8)));
typedef float f32x4  __attribute__((ext_vector_type(4)));
typedef int   int2v  __attribute__((ext_vector_type(2)));

__device__ __forceinline__ float b2f(short s) {
    union { float f; unsigned u; } c;
    c.u = ((unsigned)(unsigned short)s) << 16;
    return c.f;
}

// ---------------------------------------------------------------------------
__global__ __launch_bounds__(256) void k_params(
    const float* __restrict__ log_dt, const float* __restrict__ log_A_re,
    const float* __restrict__ A_im, const float* __restrict__ C_re,
    const float* __restrict__ C_im, float* __restrict__ ws)
{
    int idx = blockIdx.x * 256 + threadIdx.x;     // over NL*H*N2
    if (idx >= NL_ * H_ * N2_) return;
    int i  = idx / (H_ * N2_);
    int hh = (idx / N2_) % H_;
    float dt  = expf(log_dt[i * H_ + hh]);
    float Are = -expf(log_A_re[idx]);
    float Aim = A_im[idx];
    float zre = dt * Are, zim = dt * Aim;
    float er  = expf(zre);
    float wre = er * cosf(zim), wim = er * sinf(zim);
    float d   = Are * Are + Aim * Aim;
    float nre = wre - 1.f, nim = wim;
    float qre = (nre * Are + nim * Aim) / d;
    float qim = (nim * Are - nre * Aim) / d;
    float cr = C_re[idx], ci = C_im[idx];
    float ctre = cr * qre - ci * qim;
    float ctim = cr * qim + ci * qre;
    float er2 = expf(zre * (float)LC);
    float wlre = er2 * cosf(zim * (float)LC);
    float wlim = er2 * sinf(zim * (float)LC);
    ((float2*)(ws + OFF_PW))[idx]   = make_float2(wre, wim);
    ((float2*)(ws + OFF_PCT))[idx]  = make_float2(2.f * ctre, 2.f * ctim);
    ((float2*)(ws + OFF_PWLC))[idx] = make_float2(wlre, wlim);
    ((float2*)(ws + OFF_PZ))[idx]   = make_float2(zre, zim);
}

// ---------------------------------------------------------------------------
// per-channel bf16 matrices: Ttr[t][j]=k[t-j], Wtr[m][j], Vtr[t][m]
__global__ __launch_bounds__(256) void k_mats(const float* __restrict__ ws,
    int layer, __hip_bfloat16* __restrict__ mt, __hip_bfloat16* __restrict__ mw,
    __hip_bfloat16* __restrict__ mv)
{
    int h = blockIdx.x, tid = threadIdx.x;
    __shared__ float zre[32], zim[32], ctr[32], cti[32], kv[64];
    if (tid < 32) {
        float2 z = ((const float2*)(ws + OFF_PZ))[(size_t)layer*H_*N2_ + h*N2_ + tid];
        float2 c = ((const float2*)(ws + OFF_PCT))[(size_t)layer*H_*N2_ + h*N2_ + tid];
        zre[tid] = z.x; zim[tid] = z.y; ctr[tid] = c.x; cti[tid] = c.y;
    }
    __syncthreads();
    if (tid < 64) {
        float d = (float)tid, acc = 0.f;
        for (int n = 0; n < 32; n++) {
            float er = expf(zre[n] * d);
            float co = cosf(zim[n] * d), si = sinf(zim[n] * d);
            acc += er * (ctr[n] * co - cti[n] * si);
        }
        kv[tid] = acc;
    }
    __syncthreads();
    {   // Ttr
        int t = tid >> 2, j0 = (tid & 3) * 16;
        alignas(16) __hip_bfloat16 row[16];
        #pragma unroll
        for (int jj = 0; jj < 16; jj++) {
            int j = j0 + jj;
            row[jj] = __float2bfloat16(j <= t ? kv[t - j] : 0.f);
        }
        *(short8*)(mt + (size_t)h*4096 + t*64 + j0)     = *(short8*)&row[0];
        *(short8*)(mt + (size_t)h*4096 + t*64 + j0 + 8) = *(short8*)&row[8];
    }
    {   // Wtr
        int n = tid >> 3, j0 = (tid & 7) * 8;
        alignas(16) __hip_bfloat16 rre[8], rim[8];
        #pragma unroll
        for (int jj = 0; jj < 8; jj++) {
            float e = (float)(63 - (j0 + jj));
            float er = expf(zre[n] * e);
            rre[jj] = __float2bfloat16(er * cosf(zim[n] * e));
            rim[jj] = __float2bfloat16(er * sinf(zim[n] * e));
        }
        *(short8*)(mw + (size_t)h*4096 + (2*n)*64 + j0)   = *(short8*)&rre[0];
        *(short8*)(mw + (size_t)h*4096 + (2*n+1)*64 + j0) = *(short8*)&rim[0];
    }
    {   // Vtr
        int t = tid >> 2, n0 = (tid & 3) * 8;
        float e = (float)(t + 1);
        alignas(16) __hip_bfloat16 row[16];
        #pragma unroll
        for (int k = 0; k < 8; k++) {
            int n = n0 + k;
            float er = expf(zre[n] * e);
            float wr = er * cosf(zim[n] * e), wi = er * sinf(zim[n] * e);
            row[2*k]   = __float2bfloat16(ctr[n]*wr - cti[n]*wi);
            row[2*k+1] = __float2bfloat16(-(ctr[n]*wi + cti[n]*wr));
        }
        *(short8*)(mv + (size_t)h*4096 + t*64 + 2*n0)     = *(short8*)&row[0];
        *(short8*)(mv + (size_t)h*4096 + t*64 + 2*n0 + 8) = *(short8*)&row[8];
    }
}

// ---------------------------------------------------------------------------
__global__ __launch_bounds__(256) void k_transpose(const float* __restrict__ src,
    float* __restrict__ dst, int R, int Cc)
{
    __shared__ float t[32][33];
    int x = blockIdx.x * 32 + threadIdx.x;
    #pragma unroll
    for (int i = 0; i < 4; i++) {
        int yy = blockIdx.y * 32 + threadIdx.y + i * 8;
        if (x < Cc && yy < R) t[threadIdx.y + i * 8][threadIdx.x] = src[(size_t)yy * Cc + x];
    }
    __syncthreads();
    int xo = blockIdx.y * 32 + threadIdx.x;
    #pragma unroll
    for (int i = 0; i < 4; i++) {
        int yo = blockIdx.x * 32 + threadIdx.y + i * 8;
        if (xo < R && yo < Cc) dst[(size_t)yo * R + xo] = t[threadIdx.x][threadIdx.y + i * 8];
    }
}

// ---------------------------------------------------------------------------
__global__ __launch_bounds__(256) void k_wcvt(const float* __restrict__ src,
    __hip_bfloat16* __restrict__ dst, int n4)
{
    int i = blockIdx.x * 256 + threadIdx.x;
    if (i >= n4) return;
    float4 v = ((const float4*)src)[i];
    union { __hip_bfloat16 b[4]; uint2 u; } o;
    o.b[0] = __float2bfloat16(v.x); o.b[1] = __float2bfloat16(v.y);
    o.b[2] = __float2bfloat16(v.z); o.b[3] = __float2bfloat16(v.w);
    ((uint2*)dst)[i] = o.u;
}

// ---------------------------------------------------------------------------
// encoder: h = x @ encWT + b; writes u bf16 channel-major
__global__ __launch_bounds__(256) void k_encoder(const float* __restrict__ x,
    const float* __restrict__ encWT, const float* __restrict__ enc_b,
    __hip_bfloat16* __restrict__ u)
{
    __shared__ float As[DIN][36];
    __shared__ float Bs[32][268];          // B-tiles; later f32 stage [32 pos][256 ch]
    int m0e = blockIdx.x * 32;
    int tid = threadIdx.x;
    const float4* x4 = (const float4*)x;
    #pragma unroll
    for (int q = 0; q < 2; q++) {
        int f = tid * 2 + q;
        int row = f >> 4, kq = f & 15;
        float4 v = x4[(size_t)(m0e + row) * 16 + kq];
        As[kq * 4 + 0][row] = v.x; As[kq * 4 + 1][row] = v.y;
        As[kq * 4 + 2][row] = v.z; As[kq * 4 + 3][row] = v.w;
    }
    int tx = tid & 31, ty = tid >> 5;
    float acc[4][8];
    #pragma unroll
    for (int p = 0; p < 4; p++)
        #pragma unroll
        for (int j = 0; j < 8; j++) acc[p][j] = 0.f;
    const float4* w4 = (const float4*)encWT;
    for (int ks = 0; ks < 2; ks++) {
        __syncthreads();
        #pragma unroll
        for (int it = 0; it < 8; it++) {
            int q = it * 256 + tid;
            int row = q >> 6, c4 = q & 63;
            *(float4*)&Bs[row][c4 * 4] = w4[ks * 2048 + q];
        }
        __syncthreads();
        #pragma unroll 8
        for (int kk = 0; kk < 32; kk++) {
            int k = ks * 32 + kk;
            float4 a  = *(const float4*)&As[k][ty * 4];
            float4 b0 = *(const float4*)&Bs[kk][tx * 4];
            float4 b1 = *(const float4*)&Bs[kk][128 + tx * 4];
            float av[4] = {a.x, a.y, a.z, a.w};
            float bv[8] = {b0.x, b0.y, b0.z, b0.w, b1.x, b1.y, b1.z, b1.w};
            #pragma unroll
            for (int p = 0; p < 4; p++)
                #pragma unroll
                for (int j = 0; j < 8; j++)
                    acc[p][j] = fmaf(av[p], bv[j], acc[p][j]);
        }
    }
    float4 eb0 = *(const float4*)&enc_b[tx * 4];
    float4 eb1 = *(const float4*)&enc_b[128 + tx * 4];
    float ebv[8] = {eb0.x, eb0.y, eb0.z, eb0.w, eb1.x, eb1.y, eb1.z, eb1.w};
    __syncthreads();                       // Bs dead -> f32 stage st2[pl][ch]
    #pragma unroll
    for (int p = 0; p < 4; p++) {
        int pl = ty * 4 + p;
        #pragma unroll
        for (int j = 0; j < 4; j++) Bs[pl][tx * 4 + j]       = acc[p][j] + ebv[j];
        #pragma unroll
        for (int j = 0; j < 4; j++) Bs[pl][128 + tx * 4 + j] = acc[p][j + 4] + ebv[j + 4];
    }
    __syncthreads();
    // u write: thread = channel
    {
        alignas(16) __hip_bfloat16 row[32];
        #pragma unroll
        for (int pl = 0; pl < 32; pl++) row[pl] = __float2bfloat16(Bs[pl][tid]);
        #pragma unroll
        for (int q = 0; q < 4; q++)
            *(short8*)(u + (size_t)tid * M_ + m0e + q * 8) = *(short8*)&row[q * 8];
    }
}

// ---------------------------------------------------------------------------
// FUSED SSM: block = (channel, batch). u staged in XOR-swizzled LDS.
// Phase1: chunk-state MFMA -> swz LDS. Phase2: 8-way segmented scan. Phase3:
// conv MFMA + carry + GELU. swizzle: elem e of chunk c at c*64 + (e^((c&7)<<3))
__global__ __launch_bounds__(256) void k_ssm(const __hip_bfloat16* __restrict__ ucm,
    const __hip_bfloat16* __restrict__ mt, const __hip_bfloat16* __restrict__ mw,
    const __hip_bfloat16* __restrict__ mv, const float* __restrict__ ws, int layer,
    const float* __restrict__ Dp, __hip_bfloat16* __restrict__ ycm)
{
    __shared__ __hip_bfloat16 ulds[L_];       // 16 KB swizzled u
    __shared__ __hip_bfloat16 st[CHK * 64];   // 16 KB swizzled states
    __shared__ float segT[8][32][2];          // 2 KB segment totals
    int h = blockIdx.x >> 2, b = blockIdx.x & 3;
    int tid = threadIdx.x, w = tid >> 6, l = tid & 63, l15 = l & 15, l4 = l >> 4;
    const __hip_bfloat16* ub = ucm + (size_t)h * M_ + (size_t)b * L_;
    #pragma unroll
    for (int it = 0; it < 4; it++) {
        int e0 = it * 2048 + tid * 8;
        short8 v = *(const short8*)(ub + e0);
        int c = e0 >> 6, e = e0 & 63;
        *(short8*)&ulds[c * 64 + (e ^ ((c & 7) << 3))] = v;
    }
    __syncthreads();
    {
        const __hip_bfloat16* bbase = mw + (size_t)h * 4096 + l15 * 64 + l4 * 8;
        #pragma unroll
        for (int half = 0; half < 2; half++) {
            int g0 = (w + half * 4) * 16;
            int ca = g0 + l15;
            f32x4 acc[4];
            #pragma unroll
            for (int nj = 0; nj < 4; nj++) acc[nj] = (f32x4)0.f;
            #pragma unroll
            for (int ks = 0; ks < 2; ks++) {
                int e = l4 * 8 + ks * 32;
                bf16x8 a = *(const bf16x8*)&ulds[ca * 64 + (e ^ ((ca & 7) << 3))];
                #pragma unroll
                for (int nj = 0; nj < 4; nj++) {
                    bf16x8 bb = *(const bf16x8*)(bbase + nj * 16 * 64 + ks * 32);
                    acc[nj] = __builtin_amdgcn_mfma_f32_16x16x32_bf16(a, bb, acc[nj], 0, 0, 0);
                }
            }
            #pragma unroll
            for (int nj = 0; nj < 4; nj++)
                #pragma unroll
                for (int r = 0; r < 4; r++) {
                    int c = g0 + l4 * 4 + r, e = nj * 16 + l15;
                    st[c * 64 + (e ^ ((c & 7) << 3))] = __float2bfloat16(acc[nj][r]);
                }
        }
    }
    __syncthreads();
    {
        int s = tid >> 5, n = tid & 31;
        float2 wl = ((const float2*)(ws + OFF_PWLC))[(size_t)layer * H_ * N2_ + h * 32 + n];
        float tr = 0.f, ti = 0.f;
        for (int j = 0; j < 16; j++) {
            int c = s * 16 + j;
            __hip_bfloat162* p = (__hip_bfloat162*)&st[c * 64 + ((2 * n) ^ ((c & 7) << 3))];
            float2 v = __bfloat1622float2(*p);
            float nr = fmaf(wl.x, tr, v.x); nr = fmaf(-wl.y, ti, nr);
            float ni = fmaf(wl.x, ti, v.y); ni = fmaf(wl.y, tr, ni);
            tr = nr; ti = ni;
        }
        segT[s][n][0] = tr; segT[s][n][1] = ti;
        __syncthreads();
        float wr = wl.x, wi = wl.y;
        #pragma unroll
        for (int q = 0; q < 4; q++) {
            float nr = wr * wr - wi * wi, ni = 2.f * wr * wi;
            wr = nr; wi = ni;
        }
        float ar = 0.f, ai = 0.f;
        for (int t = 0; t < s; t++) {
            float Tx = segT[t][n][0], Ty = segT[t][n][1];
            float nr = fmaf(wr, ar, Tx); nr = fmaf(-wi, ai, nr);
            float ni = fmaf(wr, ai, Ty); ni = fmaf(wi, ar, ni);
            ar = nr; ai = ni;
        }
        for (int j = 0; j < 16; j++) {
            int c = s * 16 + j;
            __hip_bfloat162* p = (__hip_bfloat162*)&st[c * 64 + ((2 * n) ^ ((c & 7) << 3))];
            float2 v = __bfloat1622float2(*p);
            *p = __float22bfloat162_rn(make_float2(ar, ai));
            float nr = fmaf(wl.x, ar, v.x); nr = fmaf(-wl.y, ai, nr);
            float ni = fmaf(wl.x, ai, v.y); ni = fmaf(wl.y, ar, ni);
            ar = nr; ai = ni;
        }
    }
    __syncthreads();
    {
        const __hip_bfloat16* bt = mt + (size_t)h * 4096 + l15 * 64 + l4 * 8;
        const __hip_bfloat16* bv = mv + (size_t)h * 4096 + l15 * 64 + l4 * 8;
        float Dh = Dp[layer * H_ + h];
        __hip_bfloat16* yb = ycm + (size_t)h * M_ + (size_t)b * L_;
        #pragma unroll
        for (int half = 0; half < 2; half++) {
            int g0 = (w + half * 4) * 16;
            int ca = g0 + l15;
            f32x4 acc[4];
            #pragma unroll
            for (int nj = 0; nj < 4; nj++) acc[nj] = (f32x4)0.f;
            #pragma unroll
            for (int ks = 0; ks < 2; ks++) {
                int e = l4 * 8 + ks * 32;
                bf16x8 a = *(const bf16x8*)&ulds[ca * 64 + (e ^ ((ca & 7) << 3))];
                #pragma unroll
                for (int nj = 0; nj < 4; nj++) {
                    bf16x8 bb = *(const bf16x8*)(bt + nj * 16 * 64 + ks * 32);
                    acc[nj] = __builtin_amdgcn_mfma_f32_16x16x32_bf16(a, bb, acc[nj], 0, 0, 0);
                }
            }
            #pragma unroll
            for (int ks = 0; ks < 2; ks++) {
                int e = l4 * 8 + ks * 32;
                bf16x8 a = *(const bf16x8*)&st[ca * 64 + (e ^ ((ca & 7) << 3))];
                #pragma unroll
                for (int nj = 0; nj < 4; nj++) {
                    bf16x8 bb = *(const bf16x8*)(bv + nj * 16 * 64 + ks * 32);
                    acc[nj] = __builtin_amdgcn_mfma_f32_16x16x32_bf16(a, bb, acc[nj], 0, 0, 0);
                }
            }
            #pragma unroll
            for (int nj = 0; nj < 4; nj++)
                #pragma unroll
                for (int r = 0; r < 4; r++) {
                    int g = g0 + l4 * 4 + r;
                    int e = nj * 16 + l15;
                    float uv = __bfloat162float(ulds[g * 64 + (e ^ ((g & 7) << 3))]);
                    float v = fmaf(Dh, uv, acc[nj][r]);
                    float gg = 0.7978845608028654f * fmaf(0.044715f * v, v * v, v);
                    float yv = v / (1.f + __expf(-2.f * gg));
                    yb[(size_t)g * 64 + nj * 16 + l15] = __float2bfloat16(yv);
                }
        }
    }
}

// ---------------------------------------------------------------------------
// fused MFMA GLU+LN v12: grid 512, 2 pipelined 32-pos tiles per block.
// A/R staged from channel-major into pair-interleaved LDS; tile1's global
// loads issued under tile0's compute. u updated in-place.
__global__ __launch_bounds__(256) void k_glu_mfma(
    const __hip_bfloat16* __restrict__ ycm,  // [H][M] bf16 cm (A operand)
    const __hip_bfloat16* __restrict__ wob,  // [512,256] bf16
    const float* __restrict__ bo, const float* __restrict__ lnw,
    const float* __restrict__ lnb,
    __hip_bfloat16* __restrict__ u)          // [H][M] bf16 cm in/out (residual)
{
    __shared__ int buf[8320];                // bufA[4160] + bufR[4160]; lt alias
    __shared__ float red[4][32][2];
    int* bufA = buf;
    int* bufR = buf + 4160;
    int tid = threadIdx.x;
    int w = tid >> 6, l = tid & 63, l15 = l & 15, l4 = l >> 4;
    int mb = blockIdx.x * 64;
    int nv = w * 64;
    int p = tid & 127, ph = tid >> 7;
    const __hip_bfloat16* aB = ycm + (size_t)(2 * p) * M_ + mb + ph * 16;
    const __hip_bfloat16* rB = u + (size_t)(2 * p) * M_ + mb + ph * 16;

    // issue tile0 A/R and tile1 A loads up front
    short8 A0[4], R0[4], A1[4], R1[4];
    A0[0] = *(const short8*)(aB);          A0[1] = *(const short8*)(aB + 8);
    A0[2] = *(const short8*)(aB + M_);     A0[3] = *(const short8*)(aB + M_ + 8);
    R0[0] = *(const short8*)(rB);          R0[1] = *(const short8*)(rB + 8);
    R0[2] = *(const short8*)(rB + M_);     R0[3] = *(const short8*)(rB + M_ + 8);
    A1[0] = *(const short8*)(aB + 32);     A1[1] = *(const short8*)(aB + 40);
    A1[2] = *(const short8*)(aB + M_ + 32);A1[3] = *(const short8*)(aB + M_ + 40);

    // LN/bias params (shared by both tiles)
    float bov[4], bog[4], lw[4], lb[4];
    #pragma unroll
    for (int nj = 0; nj < 4; nj++) {
        int cn = nv + nj * 16 + l15;
        bov[nj] = bo[cn]; bog[nj] = bo[256 + cn];
        lw[nj] = lnw[cn]; lb[nj] = lnb[cn];
    }

    // stage tile0
    {
        int* da = bufA + ph * 16 * 130 + p;
        int* dr = bufR + ph * 16 * 130 + p;
        #pragma unroll
        for (int j = 0; j < 8; j++) {
            da[j * 130]       = ((int)(unsigned short)A0[0][j]) | (((int)(unsigned short)A0[2][j]) << 16);
            da[(8 + j) * 130] = ((int)(unsigned short)A0[1][j]) | (((int)(unsigned short)A0[3][j]) << 16);
            dr[j * 130]       = ((int)(unsigned short)R0[0][j]) | (((int)(unsigned short)R0[2][j]) << 16);
            dr[(8 + j) * 130] = ((int)(unsigned short)R0[1][j]) | (((int)(unsigned short)R0[3][j]) << 16);
        }
    }
    __syncthreads();

    int abase0 = l15 * 130 + l4 * 4;
    #pragma unroll
    for (int tile = 0; tile < 2; tile++) {
        int m0 = mb + tile * 32;
        f32x4 accv[2][4], accg[2][4];
        #pragma unroll
        for (int sub = 0; sub < 2; sub++)
            #pragma unroll
            for (int nj = 0; nj < 4; nj++) { accv[sub][nj] = (f32x4)0.f; accg[sub][nj] = (f32x4)0.f; }

        #pragma unroll 2
        for (int ks = 0; ks < 8; ks++) {
            int k0 = ks * 32 + l4 * 8;
            union { int2v d[2]; bf16x8 v; } a0u, a1u;
            a0u.d[0] = *(const int2v*)&bufA[abase0 + ks * 16];
            a0u.d[1] = *(const int2v*)&bufA[abase0 + ks * 16 + 2];
            a1u.d[0] = *(const int2v*)&bufA[abase0 + 16 * 130 + ks * 16];
            a1u.d[1] = *(const int2v*)&bufA[abase0 + 16 * 130 + ks * 16 + 2];
            bf16x8 a0 = a0u.v;
            bf16x8 a1 = a1u.v;
            #pragma unroll
            for (int nj = 0; nj < 4; nj++) {
                bf16x8 bv = *(const bf16x8*)(wob + (size_t)(nv + nj * 16 + l15) * H_ + k0);
                bf16x8 bg = *(const bf16x8*)(wob + (size_t)(256 + nv + nj * 16 + l15) * H_ + k0);
                accv[0][nj] = __builtin_amdgcn_mfma_f32_16x16x32_bf16(a0, bv, accv[0][nj], 0, 0, 0);
                accg[0][nj] = __builtin_amdgcn_mfma_f32_16x16x32_bf16(a0, bg, accg[0][nj], 0, 0, 0);
                accv[1][nj] = __builtin_amdgcn_mfma_f32_16x16x32_bf16(a1, bv, accv[1][nj], 0, 0, 0);
                accg[1][nj] = __builtin_amdgcn_mfma_f32_16x16x32_bf16(a1, bg, accg[1][nj], 0, 0, 0);
            }
        }

        const short* bufRs = (const short*)bufR;
        #pragma unroll
        for (int sub = 0; sub < 2; sub++) {
            #pragma unroll
            for (int r = 0; r < 4; r++) {
                int lr = sub * 16 + l4 * 4 + r;
                float s = 0.f, ss = 0.f;
                #pragma unroll
                for (int nj = 0; nj < 4; nj++) {
                    int cn = nv + nj * 16 + l15;
                    float uv = accv[sub][nj][r] + bov[nj];
                    float ug = accg[sub][nj][r] + bog[nj];
                    float z = uv / (1.f + __expf(-ug));
                    float v = z + b2f(bufRs[lr * 260 + cn]);
                    accv[sub][nj][r] = v;
                    s += v; ss += v * v;
                }
                #pragma unroll
                for (int off = 1; off < 16; off <<= 1) {
                    s  += __shfl_xor(s, off);
                    ss += __shfl_xor(ss, off);
                }
                if (l15 == 0) { red[w][lr][0] = s; red[w][lr][1] = ss; }
            }
        }
        if (tile == 0) {   // issue tile1 residual loads under tile0 epilogue
            R1[0] = *(const short8*)(rB + 32);      R1[1] = *(const short8*)(rB + 40);
            R1[2] = *(const short8*)(rB + M_ + 32); R1[3] = *(const short8*)(rB + M_ + 40);
        }
        __syncthreads();             // red ready; bufA/bufR dead -> lt alias
        short* lt = (short*)buf;
        #pragma unroll
        for (int sub = 0; sub < 2; sub++) {
            #pragma unroll
            for (int r = 0; r < 4; r++) {
                int lr = sub * 16 + l4 * 4 + r;
                float s  = red[0][lr][0] + red[1][lr][0] + red[2][lr][0] + red[3][lr][0];
                float ss = red[0][lr][1] + red[1][lr][1] + red[2][lr][1] + red[3][lr][1];
                float mu = s * (1.f / 256.f);
                float var = ss * (1.f / 256.f) - mu * mu;
                float rstd = rsqrtf(var + 1e-5f);
                #pragma unroll
                for (int nj = 0; nj < 4; nj++) {
                    int cn = nv + nj * 16 + l15;
                    float val = (accv[sub][nj][r] - mu) * rstd * lw[nj] + lb[nj];
                    __hip_bfloat16 bval = __float2bfloat16(val);
                    lt[cn * 34 + lr] = *(short*)&bval;
                }
            }
        }
        __syncthreads();             // lt complete
        #pragma unroll
        for (int q = 0; q < 4; q++)
            *(short8*)(u + (size_t)tid * M_ + m0 + q * 8)
                = *(short8*)&lt[tid * 34 + q * 8];
        if (tile == 0) {
            __syncthreads();         // lt reads done -> restage bufA/bufR
            int* da = bufA + ph * 16 * 130 + p;
            int* dr = bufR + ph * 16 * 130 + p;
            #pragma unroll
            for (int j = 0; j < 8; j++) {
                da[j * 130]       = ((int)(unsigned short)A1[0][j]) | (((int)(unsigned short)A1[2][j]) << 16);
                da[(8 + j) * 130] = ((int)(unsigned short)A1[1][j]) | (((int)(unsigned short)A1[3][j]) << 16);
                dr[j * 130]       = ((int)(unsigned short)R1[0][j]) | (((int)(unsigned short)R1[2][j]) << 16);
                dr[(8 + j) * 130] = ((int)(unsigned short)R1[1][j]) | (((int)(unsigned short)R1[3][j]) << 16);
            }
            __syncthreads();
        }
    }
}

// ---------------------------------------------------------------------------
// decoder: stages u (cm) via pair-interleaved dword LDS (coalesced 64B rows)
__global__ __launch_bounds__(256) void k_decoder(const __hip_bfloat16* __restrict__ u,
    const float* __restrict__ out_W, const float* __restrict__ out_b,
    float* __restrict__ out)
{
    __shared__ int ds[64 * 130];             // [pos][130] pair-interleaved
    __shared__ float wl[10][260];
    int m0 = blockIdx.x * 64;
    int tid = threadIdx.x;
    {   // thread = (pair p, pos-half ph): 2 channels x 32 positions (64B rows)
        int p = tid & 127, ph = tid >> 7;
        const __hip_bfloat16* s0 = u + (size_t)(2 * p) * M_ + m0 + ph * 32;
        const __hip_bfloat16* s1 = s0 + M_;
        short8 y0[4], y1[4];
        #pragma unroll
        for (int q = 0; q < 4; q++) {
            y0[q] = *(const short8*)(s0 + q * 8);
            y1[q] = *(const short8*)(s1 + q * 8);
        }
        int* dst = ds + (ph * 32) * 130 + p;
        #pragma unroll
        for (int q = 0; q < 4; q++)
            #pragma unroll
            for (int j = 0; j < 8; j++)
                dst[(q * 8 + j) * 130] =
                    ((int)(unsigned short)y0[q][j]) | (((int)(unsigned short)y1[q][j]) << 16);
    }
    for (int q = tid; q < 640; q += 256) {
        int r = q / 64, k4 = q % 64;
        *(float4*)&wl[r][k4 * 4] = ((const float4*)out_W)[q];
    }
    __syncthreads();
    int slot = tid & 15;
    if (slot < DOUT) {
        #pragma unroll
        for (int pass = 0; pass < 4; pass++) {
            int pl = pass * 16 + (tid >> 4);
            const int* row = ds + pl * 130;
            float a0 = 0.f, a1 = 0.f;
            #pragma unroll 8
            for (int d = 0; d < 128; d++) {
                int v = row[d];
                a0 = fmaf(b2f((short)(v & 0xffff)),  wl[slot][2 * d],     a0);
                a1 = fmaf(b2f((short)(v >> 16)),     wl[slot][2 * d + 1], a1);
            }
            out[(size_t)(m0 + pl) * DOUT + slot] = a0 + a1 + out_b[slot];
        }
    }
}

// ---------------------------------------------------------------------------
extern "C" void kernel_launch(void* const* d_in, const int* in_sizes, int n_in,
                              void* d_out, int out_size, void* d_ws, size_t ws_size,
                              hipStream_t stream)
{
    (void)in_sizes; (void)n_in; (void)out_size; (void)ws_size;
    const float* x        = (const float*)d_in[0];
    const float* enc_W    = (const float*)d_in[1];
    const float* enc_b    = (const float*)d_in[2];
    const float* log_dt   = (const float*)d_in[3];
    const float* log_A_re = (const float*)d_in[4];
    const float* A_im     = (const float*)d_in[5];
    const float* C_re     = (const float*)d_in[6];
    const float* C_im     = (const float*)d_in[7];
    const float* Dp       = (const float*)d_in[8];
    const float* Wo       = (const float*)d_in[9];
    const float* bo       = (const float*)d_in[10];
    const float* lnw      = (const float*)d_in[11];
    const float* lnb      = (const float*)d_in[12];
    const float* out_W    = (const float*)d_in[13];
    const float* out_b    = (const float*)d_in[14];
    float* ws = (float*)d_ws;
    __hip_bfloat16* u   = (__hip_bfloat16*)(ws + OFF_UCM);
    __hip_bfloat16* ycm = (__hip_bfloat16*)(ws + OFF_YCM);
    __hip_bfloat16* mt = (__hip_bfloat16*)(ws + OFF_MT);
    __hip_bfloat16* mw = (__hip_bfloat16*)(ws + OFF_MW);
    __hip_bfloat16* mv = (__hip_bfloat16*)(ws + OFF_MV);
    __hip_bfloat16* wob = (__hip_bfloat16*)(ws + OFF_WOB);

    k_params<<<NL_ * H_ * N2_ / 256, 256, 0, stream>>>(log_dt, log_A_re, A_im, C_re, C_im, ws);
    dim3 tb(32, 8);
    k_transpose<<<dim3(DIN / 32, H_ / 32), tb, 0, stream>>>(enc_W, ws + OFF_EWT, H_, DIN);
    k_wcvt<<<(NL_ * 2 * H_ * H_ / 4 + 255) / 256, 256, 0, stream>>>(Wo, wob, NL_ * 2 * H_ * H_ / 4);
    k_encoder<<<M_ / 32, 256, 0, stream>>>(x, ws + OFF_EWT, enc_b, u);
    for (int i = 0; i < NL_; i++) {
        k_mats<<<H_, 256, 0, stream>>>(ws, i, mt, mw, mv);
        k_ssm<<<H_ * B_, 256, 0, stream>>>(u, mt, mw, mv, ws, i, Dp, ycm);
        k_glu_mfma<<<M_ / 64, 256, 0, stream>>>(ycm,
            wob + (size_t)i * 2 * H_ * H_, bo + (size_t)i * 2 * H_,
            lnw + (size_t)i * H_, lnb + (size_t)i * H_, u);
    }
    k_decoder<<<M_ / 64, 256, 0, stream>>>(u, out_W, out_b, (float*)d_out);
}

// Round 16
// 366.476 us; speedup vs baseline: 1.2254x; 1.1429x over previous
//
#include <hip/hip_runtime.h>
#include <hip/hip_bf16.h>

// ---------------------------------------------------------------------------
// S4D stack, MFMA everywhere, single in-place state buffer u (bf16 [H][M]):
// prep: params; cvt(Wo,x,enc_W)->bf16; mats_all (all layers).
// encoder MFMA(->u cm) -> 4x[ fused SSM (u->LDS swz, state MFMA + segmented
//   LDS scan + Toeplitz conv MFMA -> ycm); GLU MFMA + LN v12 (2-tile
//   pipelined, A/R staged from cm via pair-interleaved LDS; u in-place) ]
// -> decoder (pair-interleaved staging).
// glu LDS: dword[pos][130]: dword p of row pos = short2(ch 2p, ch 2p+1)
// ---------------------------------------------------------------------------

constexpr int B_ = 4, L_ = 8192, DIN = 64, H_ = 256, N2_ = 32, NL_ = 4, DOUT = 10;
constexpr int LC = 64, CHK = L_ / LC;     // 128 chunks/batch
constexpr int GCH = B_ * CHK;             // 512 global chunks
constexpr int M_ = B_ * L_;               // 32768 positions

// ws layout in float slots
constexpr size_t OFF_XB   = 0;                         // bf16 x [M*64]
constexpr size_t OFF_EWB  = 1048576;                   // bf16 enc_W [256*64]
constexpr size_t OFF_WOB  = 8388608;                   // bf16 Wo NL*512*256
constexpr size_t OFF_PW   = 8650752;                   // (legacy)
constexpr size_t OFF_PCT  = 8716288;                   // f32 Ct2 pairs
constexpr size_t OFF_PWLC = 8781824;                   // f32 w^64 pairs
constexpr size_t OFF_PZ   = 8847360;                   // f32 z=dtA pairs
constexpr size_t OFF_UCM  = 8929280;                   // bf16 [H][M] u (in-place)
constexpr size_t OFF_YCM  = 13123584;                  // bf16 [H][M] y cm
constexpr size_t OFF_MTA  = 17317888;                  // bf16 Ttr [NL][H][64][64]
constexpr size_t OFF_MWA  = 19415040;                  // bf16 Wtr [NL][H][64][64]
constexpr size_t OFF_MVA  = 21512192;                  // bf16 Vtr [NL][H][64][64]
// end 23609344 slots = 94.4 MB (proven in r4/r5)

typedef short bf16x8 __attribute__((ext_vector_type(8)));
typedef short short8 __attribute__((ext_vector_type(8)));
typedef float f32x4  __attribute__((ext_vector_type(4)));
typedef int   int2v  __attribute__((ext_vector_type(2)));

__device__ __forceinline__ float b2f(short s) {
    union { float f; unsigned u; } c;
    c.u = ((unsigned)(unsigned short)s) << 16;
    return c.f;
}

// ---------------------------------------------------------------------------
__global__ __launch_bounds__(256) void k_params(
    const float* __restrict__ log_dt, const float* __restrict__ log_A_re,
    const float* __restrict__ A_im, const float* __restrict__ C_re,
    const float* __restrict__ C_im, float* __restrict__ ws)
{
    int idx = blockIdx.x * 256 + threadIdx.x;     // over NL*H*N2
    if (idx >= NL_ * H_ * N2_) return;
    int i  = idx / (H_ * N2_);
    int hh = (idx / N2_) % H_;
    float dt  = expf(log_dt[i * H_ + hh]);
    float Are = -expf(log_A_re[idx]);
    float Aim = A_im[idx];
    float zre = dt * Are, zim = dt * Aim;
    float er  = expf(zre);
    float wre = er * cosf(zim), wim = er * sinf(zim);
    float d   = Are * Are + Aim * Aim;
    float nre = wre - 1.f, nim = wim;
    float qre = (nre * Are + nim * Aim) / d;
    float qim = (nim * Are - nre * Aim) / d;
    float cr = C_re[idx], ci = C_im[idx];
    float ctre = cr * qre - ci * qim;
    float ctim = cr * qim + ci * qre;
    float er2 = expf(zre * (float)LC);
    float wlre = er2 * cosf(zim * (float)LC);
    float wlim = er2 * sinf(zim * (float)LC);
    ((float2*)(ws + OFF_PW))[idx]   = make_float2(wre, wim);
    ((float2*)(ws + OFF_PCT))[idx]  = make_float2(2.f * ctre, 2.f * ctim);
    ((float2*)(ws + OFF_PWLC))[idx] = make_float2(wlre, wlim);
    ((float2*)(ws + OFF_PZ))[idx]   = make_float2(zre, zim);
}

// ---------------------------------------------------------------------------
// ALL-LAYER per-channel bf16 matrices: Ttr[t][j]=k[t-j], Wtr[m][j], Vtr[t][m]
__global__ __launch_bounds__(256) void k_mats_all(const float* __restrict__ ws,
    __hip_bfloat16* __restrict__ mt, __hip_bfloat16* __restrict__ mw,
    __hip_bfloat16* __restrict__ mv)
{
    int bid = blockIdx.x;                  // NL*H blocks
    int layer = bid >> 8, h = bid & 255;
    int lh = layer * H_ + h;
    int tid = threadIdx.x;
    __shared__ float zre[32], zim[32], ctr[32], cti[32], kv[64];
    if (tid < 32) {
        float2 z = ((const float2*)(ws + OFF_PZ))[(size_t)lh * N2_ + tid];
        float2 c = ((const float2*)(ws + OFF_PCT))[(size_t)lh * N2_ + tid];
        zre[tid] = z.x; zim[tid] = z.y; ctr[tid] = c.x; cti[tid] = c.y;
    }
    __syncthreads();
    if (tid < 64) {
        float d = (float)tid, acc = 0.f;
        for (int n = 0; n < 32; n++) {
            float er = expf(zre[n] * d);
            float co = cosf(zim[n] * d), si = sinf(zim[n] * d);
            acc += er * (ctr[n] * co - cti[n] * si);
        }
        kv[tid] = acc;
    }
    __syncthreads();
    {   // Ttr
        int t = tid >> 2, j0 = (tid & 3) * 16;
        alignas(16) __hip_bfloat16 row[16];
        #pragma unroll
        for (int jj = 0; jj < 16; jj++) {
            int j = j0 + jj;
            row[jj] = __float2bfloat16(j <= t ? kv[t - j] : 0.f);
        }
        *(short8*)(mt + (size_t)lh*4096 + t*64 + j0)     = *(short8*)&row[0];
        *(short8*)(mt + (size_t)lh*4096 + t*64 + j0 + 8) = *(short8*)&row[8];
    }
    {   // Wtr
        int n = tid >> 3, j0 = (tid & 7) * 8;
        alignas(16) __hip_bfloat16 rre[8], rim[8];
        #pragma unroll
        for (int jj = 0; jj < 8; jj++) {
            float e = (float)(63 - (j0 + jj));
            float er = expf(zre[n] * e);
            rre[jj] = __float2bfloat16(er * cosf(zim[n] * e));
            rim[jj] = __float2bfloat16(er * sinf(zim[n] * e));
        }
        *(short8*)(mw + (size_t)lh*4096 + (2*n)*64 + j0)   = *(short8*)&rre[0];
        *(short8*)(mw + (size_t)lh*4096 + (2*n+1)*64 + j0) = *(short8*)&rim[0];
    }
    {   // Vtr
        int t = tid >> 2, n0 = (tid & 3) * 8;
        float e = (float)(t + 1);
        alignas(16) __hip_bfloat16 row[16];
        #pragma unroll
        for (int k = 0; k < 8; k++) {
            int n = n0 + k;
            float er = expf(zre[n] * e);
            float wr = er * cosf(zim[n] * e), wi = er * sinf(zim[n] * e);
            row[2*k]   = __float2bfloat16(ctr[n]*wr - cti[n]*wi);
            row[2*k+1] = __float2bfloat16(-(ctr[n]*wi + cti[n]*wr));
        }
        *(short8*)(mv + (size_t)lh*4096 + t*64 + 2*n0)     = *(short8*)&row[0];
        *(short8*)(mv + (size_t)lh*4096 + t*64 + 2*n0 + 8) = *(short8*)&row[8];
    }
}

// ---------------------------------------------------------------------------
__global__ __launch_bounds__(256) void k_wcvt(const float* __restrict__ src,
    __hip_bfloat16* __restrict__ dst, int n4)
{
    int i = blockIdx.x * 256 + threadIdx.x;
    if (i >= n4) return;
    float4 v = ((const float4*)src)[i];
    union { __hip_bfloat16 b[4]; uint2 u; } o;
    o.b[0] = __float2bfloat16(v.x); o.b[1] = __float2bfloat16(v.y);
    o.b[2] = __float2bfloat16(v.z); o.b[3] = __float2bfloat16(v.w);
    ((uint2*)dst)[i] = o.u;
}

// ---------------------------------------------------------------------------
// encoder MFMA: u[cm] = (xb @ ewb^T + b), 64 pos/block, 4 waves = col quarters
__global__ __launch_bounds__(256) void k_encoder(const __hip_bfloat16* __restrict__ xb,
    const __hip_bfloat16* __restrict__ ewb, const float* __restrict__ enc_b,
    __hip_bfloat16* __restrict__ u)
{
    __shared__ short lt[256 * 66];          // 33 KB transpose buffer
    int tid = threadIdx.x;
    int w = tid >> 6, l = tid & 63, l15 = l & 15, l4 = l >> 4;
    int m0 = blockIdx.x * 64;
    int nv = w * 64;
    f32x4 acc[4][4];
    #pragma unroll
    for (int mi = 0; mi < 4; mi++)
        #pragma unroll
        for (int nj = 0; nj < 4; nj++) acc[mi][nj] = (f32x4)0.f;
    #pragma unroll
    for (int ks = 0; ks < 2; ks++) {
        int k0 = ks * 32 + l4 * 8;
        bf16x8 a[4];
        #pragma unroll
        for (int mi = 0; mi < 4; mi++)
            a[mi] = *(const bf16x8*)(xb + (size_t)(m0 + mi * 16 + l15) * 64 + k0);
        #pragma unroll
        for (int nj = 0; nj < 4; nj++) {
            bf16x8 b = *(const bf16x8*)(ewb + (size_t)(nv + nj * 16 + l15) * 64 + k0);
            #pragma unroll
            for (int mi = 0; mi < 4; mi++)
                acc[mi][nj] = __builtin_amdgcn_mfma_f32_16x16x32_bf16(a[mi], b, acc[mi][nj], 0, 0, 0);
        }
    }
    float bov[4];
    #pragma unroll
    for (int nj = 0; nj < 4; nj++) bov[nj] = enc_b[nv + nj * 16 + l15];
    #pragma unroll
    for (int mi = 0; mi < 4; mi++)
        #pragma unroll
        for (int r = 0; r < 4; r++) {
            int lr = mi * 16 + l4 * 4 + r;
            #pragma unroll
            for (int nj = 0; nj < 4; nj++) {
                int cn = nv + nj * 16 + l15;
                __hip_bfloat16 bv = __float2bfloat16(acc[mi][nj][r] + bov[nj]);
                lt[cn * 66 + lr] = *(short*)&bv;
            }
        }
    __syncthreads();
    #pragma unroll
    for (int q = 0; q < 8; q++)
        *(short8*)(u + (size_t)tid * M_ + m0 + q * 8) = *(short8*)&lt[tid * 66 + q * 8];
}

// ---------------------------------------------------------------------------
// FUSED SSM: block = (channel, batch). u staged in XOR-swizzled LDS.
// Phase1: chunk-state MFMA -> swz LDS. Phase2: 8-way segmented scan. Phase3:
// conv MFMA + carry + GELU. swizzle: elem e of chunk c at c*64 + (e^((c&7)<<3))
__global__ __launch_bounds__(256) void k_ssm(const __hip_bfloat16* __restrict__ ucm,
    const __hip_bfloat16* __restrict__ mt, const __hip_bfloat16* __restrict__ mw,
    const __hip_bfloat16* __restrict__ mv, const float* __restrict__ ws, int layer,
    const float* __restrict__ Dp, __hip_bfloat16* __restrict__ ycm)
{
    __shared__ __hip_bfloat16 ulds[L_];       // 16 KB swizzled u
    __shared__ __hip_bfloat16 st[CHK * 64];   // 16 KB swizzled states
    __shared__ float segT[8][32][2];          // 2 KB segment totals
    int h = blockIdx.x >> 2, b = blockIdx.x & 3;
    int tid = threadIdx.x, w = tid >> 6, l = tid & 63, l15 = l & 15, l4 = l >> 4;
    const __hip_bfloat16* ub = ucm + (size_t)h * M_ + (size_t)b * L_;
    #pragma unroll
    for (int it = 0; it < 4; it++) {
        int e0 = it * 2048 + tid * 8;
        short8 v = *(const short8*)(ub + e0);
        int c = e0 >> 6, e = e0 & 63;
        *(short8*)&ulds[c * 64 + (e ^ ((c & 7) << 3))] = v;
    }
    __syncthreads();
    {
        const __hip_bfloat16* bbase = mw + (size_t)h * 4096 + l15 * 64 + l4 * 8;
        #pragma unroll
        for (int half = 0; half < 2; half++) {
            int g0 = (w + half * 4) * 16;
            int ca = g0 + l15;
            f32x4 acc[4];
            #pragma unroll
            for (int nj = 0; nj < 4; nj++) acc[nj] = (f32x4)0.f;
            #pragma unroll
            for (int ks = 0; ks < 2; ks++) {
                int e = l4 * 8 + ks * 32;
                bf16x8 a = *(const bf16x8*)&ulds[ca * 64 + (e ^ ((ca & 7) << 3))];
                #pragma unroll
                for (int nj = 0; nj < 4; nj++) {
                    bf16x8 bb = *(const bf16x8*)(bbase + nj * 16 * 64 + ks * 32);
                    acc[nj] = __builtin_amdgcn_mfma_f32_16x16x32_bf16(a, bb, acc[nj], 0, 0, 0);
                }
            }
            #pragma unroll
            for (int nj = 0; nj < 4; nj++)
                #pragma unroll
                for (int r = 0; r < 4; r++) {
                    int c = g0 + l4 * 4 + r, e = nj * 16 + l15;
                    st[c * 64 + (e ^ ((c & 7) << 3))] = __float2bfloat16(acc[nj][r]);
                }
        }
    }
    __syncthreads();
    {
        int s = tid >> 5, n = tid & 31;
        float2 wl = ((const float2*)(ws + OFF_PWLC))[(size_t)layer * H_ * N2_ + h * 32 + n];
        float tr = 0.f, ti = 0.f;
        for (int j = 0; j < 16; j++) {
            int c = s * 16 + j;
            __hip_bfloat162* p = (__hip_bfloat162*)&st[c * 64 + ((2 * n) ^ ((c & 7) << 3))];
            float2 v = __bfloat1622float2(*p);
            float nr = fmaf(wl.x, tr, v.x); nr = fmaf(-wl.y, ti, nr);
            float ni = fmaf(wl.x, ti, v.y); ni = fmaf(wl.y, tr, ni);
            tr = nr; ti = ni;
        }
        segT[s][n][0] = tr; segT[s][n][1] = ti;
        __syncthreads();
        float wr = wl.x, wi = wl.y;
        #pragma unroll
        for (int q = 0; q < 4; q++) {
            float nr = wr * wr - wi * wi, ni = 2.f * wr * wi;
            wr = nr; wi = ni;
        }
        float ar = 0.f, ai = 0.f;
        for (int t = 0; t < s; t++) {
            float Tx = segT[t][n][0], Ty = segT[t][n][1];
            float nr = fmaf(wr, ar, Tx); nr = fmaf(-wi, ai, nr);
            float ni = fmaf(wr, ai, Ty); ni = fmaf(wi, ar, ni);
            ar = nr; ai = ni;
        }
        for (int j = 0; j < 16; j++) {
            int c = s * 16 + j;
            __hip_bfloat162* p = (__hip_bfloat162*)&st[c * 64 + ((2 * n) ^ ((c & 7) << 3))];
            float2 v = __bfloat1622float2(*p);
            *p = __float22bfloat162_rn(make_float2(ar, ai));
            float nr = fmaf(wl.x, ar, v.x); nr = fmaf(-wl.y, ai, nr);
            float ni = fmaf(wl.x, ai, v.y); ni = fmaf(wl.y, ar, ni);
            ar = nr; ai = ni;
        }
    }
    __syncthreads();
    {
        const __hip_bfloat16* bt = mt + (size_t)h * 4096 + l15 * 64 + l4 * 8;
        const __hip_bfloat16* bv = mv + (size_t)h * 4096 + l15 * 64 + l4 * 8;
        float Dh = Dp[layer * H_ + h];
        __hip_bfloat16* yb = ycm + (size_t)h * M_ + (size_t)b * L_;
        #pragma unroll
        for (int half = 0; half < 2; half++) {
            int g0 = (w + half * 4) * 16;
            int ca = g0 + l15;
            f32x4 acc[4];
            #pragma unroll
            for (int nj = 0; nj < 4; nj++) acc[nj] = (f32x4)0.f;
            #pragma unroll
            for (int ks = 0; ks < 2; ks++) {
                int e = l4 * 8 + ks * 32;
                bf16x8 a = *(const bf16x8*)&ulds[ca * 64 + (e ^ ((ca & 7) << 3))];
                #pragma unroll
                for (int nj = 0; nj < 4; nj++) {
                    bf16x8 bb = *(const bf16x8*)(bt + nj * 16 * 64 + ks * 32);
                    acc[nj] = __builtin_amdgcn_mfma_f32_16x16x32_bf16(a, bb, acc[nj], 0, 0, 0);
                }
            }
            #pragma unroll
            for (int ks = 0; ks < 2; ks++) {
                int e = l4 * 8 + ks * 32;
                bf16x8 a = *(const bf16x8*)&st[ca * 64 + (e ^ ((ca & 7) << 3))];
                #pragma unroll
                for (int nj = 0; nj < 4; nj++) {
                    bf16x8 bb = *(const bf16x8*)(bv + nj * 16 * 64 + ks * 32);
                    acc[nj] = __builtin_amdgcn_mfma_f32_16x16x32_bf16(a, bb, acc[nj], 0, 0, 0);
                }
            }
            #pragma unroll
            for (int nj = 0; nj < 4; nj++)
                #pragma unroll
                for (int r = 0; r < 4; r++) {
                    int g = g0 + l4 * 4 + r;
                    int e = nj * 16 + l15;
                    float uv = __bfloat162float(ulds[g * 64 + (e ^ ((g & 7) << 3))]);
                    float v = fmaf(Dh, uv, acc[nj][r]);
                    float gg = 0.7978845608028654f * fmaf(0.044715f * v, v * v, v);
                    float yv = v / (1.f + __expf(-2.f * gg));
                    yb[(size_t)g * 64 + nj * 16 + l15] = __float2bfloat16(yv);
                }
        }
    }
}

// ---------------------------------------------------------------------------
// fused MFMA GLU+LN v12: grid 512, 2 pipelined 32-pos tiles per block.
// A/R staged from channel-major into pair-interleaved LDS; tile1's global
// loads issued under tile0's compute. u updated in-place.
__global__ __launch_bounds__(256) void k_glu_mfma(
    const __hip_bfloat16* __restrict__ ycm,  // [H][M] bf16 cm (A operand)
    const __hip_bfloat16* __restrict__ wob,  // [512,256] bf16
    const float* __restrict__ bo, const float* __restrict__ lnw,
    const float* __restrict__ lnb,
    __hip_bfloat16* __restrict__ u)          // [H][M] bf16 cm in/out (residual)
{
    __shared__ int buf[8320];                // bufA[4160] + bufR[4160]; lt alias
    __shared__ float red[4][32][2];
    int* bufA = buf;
    int* bufR = buf + 4160;
    int tid = threadIdx.x;
    int w = tid >> 6, l = tid & 63, l15 = l & 15, l4 = l >> 4;
    int mb = blockIdx.x * 64;
    int nv = w * 64;
    int p = tid & 127, ph = tid >> 7;
    const __hip_bfloat16* aB = ycm + (size_t)(2 * p) * M_ + mb + ph * 16;
    const __hip_bfloat16* rB = u + (size_t)(2 * p) * M_ + mb + ph * 16;

    // issue tile0 A/R and tile1 A loads up front
    short8 A0[4], R0[4], A1[4], R1[4];
    A0[0] = *(const short8*)(aB);          A0[1] = *(const short8*)(aB + 8);
    A0[2] = *(const short8*)(aB + M_);     A0[3] = *(const short8*)(aB + M_ + 8);
    R0[0] = *(const short8*)(rB);          R0[1] = *(const short8*)(rB + 8);
    R0[2] = *(const short8*)(rB + M_);     R0[3] = *(const short8*)(rB + M_ + 8);
    A1[0] = *(const short8*)(aB + 32);     A1[1] = *(const short8*)(aB + 40);
    A1[2] = *(const short8*)(aB + M_ + 32);A1[3] = *(const short8*)(aB + M_ + 40);

    // LN/bias params (shared by both tiles)
    float bov[4], bog[4], lw[4], lb[4];
    #pragma unroll
    for (int nj = 0; nj < 4; nj++) {
        int cn = nv + nj * 16 + l15;
        bov[nj] = bo[cn]; bog[nj] = bo[256 + cn];
        lw[nj] = lnw[cn]; lb[nj] = lnb[cn];
    }

    // stage tile0
    {
        int* da = bufA + ph * 16 * 130 + p;
        int* dr = bufR + ph * 16 * 130 + p;
        #pragma unroll
        for (int j = 0; j < 8; j++) {
            da[j * 130]       = ((int)(unsigned short)A0[0][j]) | (((int)(unsigned short)A0[2][j]) << 16);
            da[(8 + j) * 130] = ((int)(unsigned short)A0[1][j]) | (((int)(unsigned short)A0[3][j]) << 16);
            dr[j * 130]       = ((int)(unsigned short)R0[0][j]) | (((int)(unsigned short)R0[2][j]) << 16);
            dr[(8 + j) * 130] = ((int)(unsigned short)R0[1][j]) | (((int)(unsigned short)R0[3][j]) << 16);
        }
    }
    __syncthreads();

    int abase0 = l15 * 130 + l4 * 4;
    #pragma unroll
    for (int tile = 0; tile < 2; tile++) {
        int m0 = mb + tile * 32;
        f32x4 accv[2][4], accg[2][4];
        #pragma unroll
        for (int sub = 0; sub < 2; sub++)
            #pragma unroll
            for (int nj = 0; nj < 4; nj++) { accv[sub][nj] = (f32x4)0.f; accg[sub][nj] = (f32x4)0.f; }

        #pragma unroll 2
        for (int ks = 0; ks < 8; ks++) {
            int k0 = ks * 32 + l4 * 8;
            union { int2v d[2]; bf16x8 v; } a0u, a1u;
            a0u.d[0] = *(const int2v*)&bufA[abase0 + ks * 16];
            a0u.d[1] = *(const int2v*)&bufA[abase0 + ks * 16 + 2];
            a1u.d[0] = *(const int2v*)&bufA[abase0 + 16 * 130 + ks * 16];
            a1u.d[1] = *(const int2v*)&bufA[abase0 + 16 * 130 + ks * 16 + 2];
            bf16x8 a0 = a0u.v;
            bf16x8 a1 = a1u.v;
            #pragma unroll
            for (int nj = 0; nj < 4; nj++) {
                bf16x8 bv = *(const bf16x8*)(wob + (size_t)(nv + nj * 16 + l15) * H_ + k0);
                bf16x8 bg = *(const bf16x8*)(wob + (size_t)(256 + nv + nj * 16 + l15) * H_ + k0);
                accv[0][nj] = __builtin_amdgcn_mfma_f32_16x16x32_bf16(a0, bv, accv[0][nj], 0, 0, 0);
                accg[0][nj] = __builtin_amdgcn_mfma_f32_16x16x32_bf16(a0, bg, accg[0][nj], 0, 0, 0);
                accv[1][nj] = __builtin_amdgcn_mfma_f32_16x16x32_bf16(a1, bv, accv[1][nj], 0, 0, 0);
                accg[1][nj] = __builtin_amdgcn_mfma_f32_16x16x32_bf16(a1, bg, accg[1][nj], 0, 0, 0);
            }
        }

        const short* bufRs = (const short*)bufR;
        #pragma unroll
        for (int sub = 0; sub < 2; sub++) {
            #pragma unroll
            for (int r = 0; r < 4; r++) {
                int lr = sub * 16 + l4 * 4 + r;
                float s = 0.f, ss = 0.f;
                #pragma unroll
                for (int nj = 0; nj < 4; nj++) {
                    int cn = nv + nj * 16 + l15;
                    float uv = accv[sub][nj][r] + bov[nj];
                    float ug = accg[sub][nj][r] + bog[nj];
                    float z = uv / (1.f + __expf(-ug));
                    float v = z + b2f(bufRs[lr * 260 + cn]);
                    accv[sub][nj][r] = v;
                    s += v; ss += v * v;
                }
                #pragma unroll
                for (int off = 1; off < 16; off <<= 1) {
                    s  += __shfl_xor(s, off);
                    ss += __shfl_xor(ss, off);
                }
                if (l15 == 0) { red[w][lr][0] = s; red[w][lr][1] = ss; }
            }
        }
        if (tile == 0) {   // issue tile1 residual loads under tile0 epilogue
            R1[0] = *(const short8*)(rB + 32);      R1[1] = *(const short8*)(rB + 40);
            R1[2] = *(const short8*)(rB + M_ + 32); R1[3] = *(const short8*)(rB + M_ + 40);
        }
        __syncthreads();             // red ready; bufA/bufR dead -> lt alias
        short* lt = (short*)buf;
        #pragma unroll
        for (int sub = 0; sub < 2; sub++) {
            #pragma unroll
            for (int r = 0; r < 4; r++) {
                int lr = sub * 16 + l4 * 4 + r;
                float s  = red[0][lr][0] + red[1][lr][0] + red[2][lr][0] + red[3][lr][0];
                float ss = red[0][lr][1] + red[1][lr][1] + red[2][lr][1] + red[3][lr][1];
                float mu = s * (1.f / 256.f);
                float var = ss * (1.f / 256.f) - mu * mu;
                float rstd = rsqrtf(var + 1e-5f);
                #pragma unroll
                for (int nj = 0; nj < 4; nj++) {
                    int cn = nv + nj * 16 + l15;
                    float val = (accv[sub][nj][r] - mu) * rstd * lw[nj] + lb[nj];
                    __hip_bfloat16 bval = __float2bfloat16(val);
                    lt[cn * 34 + lr] = *(short*)&bval;
                }
            }
        }
        __syncthreads();             // lt complete
        #pragma unroll
        for (int q = 0; q < 4; q++)
            *(short8*)(u + (size_t)tid * M_ + m0 + q * 8)
                = *(short8*)&lt[tid * 34 + q * 8];
        if (tile == 0) {
            __syncthreads();         // lt reads done -> restage bufA/bufR
            int* da = bufA + ph * 16 * 130 + p;
            int* dr = bufR + ph * 16 * 130 + p;
            #pragma unroll
            for (int j = 0; j < 8; j++) {
                da[j * 130]       = ((int)(unsigned short)A1[0][j]) | (((int)(unsigned short)A1[2][j]) << 16);
                da[(8 + j) * 130] = ((int)(unsigned short)A1[1][j]) | (((int)(unsigned short)A1[3][j]) << 16);
                dr[j * 130]       = ((int)(unsigned short)R1[0][j]) | (((int)(unsigned short)R1[2][j]) << 16);
                dr[(8 + j) * 130] = ((int)(unsigned short)R1[1][j]) | (((int)(unsigned short)R1[3][j]) << 16);
            }
            __syncthreads();
        }
    }
}

// ---------------------------------------------------------------------------
// decoder: stages u (cm) via pair-interleaved dword LDS (coalesced 64B rows)
__global__ __launch_bounds__(256) void k_decoder(const __hip_bfloat16* __restrict__ u,
    const float* __restrict__ out_W, const float* __restrict__ out_b,
    float* __restrict__ out)
{
    __shared__ int ds[64 * 130];             // [pos][130] pair-interleaved
    __shared__ float wl[10][260];
    int m0 = blockIdx.x * 64;
    int tid = threadIdx.x;
    {   // thread = (pair p, pos-half ph): 2 channels x 32 positions (64B rows)
        int p = tid & 127, ph = tid >> 7;
        const __hip_bfloat16* s0 = u + (size_t)(2 * p) * M_ + m0 + ph * 32;
        const __hip_bfloat16* s1 = s0 + M_;
        short8 y0[4], y1[4];
        #pragma unroll
        for (int q = 0; q < 4; q++) {
            y0[q] = *(const short8*)(s0 + q * 8);
            y1[q] = *(const short8*)(s1 + q * 8);
        }
        int* dst = ds + (ph * 32) * 130 + p;
        #pragma unroll
        for (int q = 0; q < 4; q++)
            #pragma unroll
            for (int j = 0; j < 8; j++)
                dst[(q * 8 + j) * 130] =
                    ((int)(unsigned short)y0[q][j]) | (((int)(unsigned short)y1[q][j]) << 16);
    }
    for (int q = tid; q < 640; q += 256) {
        int r = q / 64, k4 = q % 64;
        *(float4*)&wl[r][k4 * 4] = ((const float4*)out_W)[q];
    }
    __syncthreads();
    int slot = tid & 15;
    if (slot < DOUT) {
        #pragma unroll
        for (int pass = 0; pass < 4; pass++) {
            int pl = pass * 16 + (tid >> 4);
            const int* row = ds + pl * 130;
            float a0 = 0.f, a1 = 0.f;
            #pragma unroll 8
            for (int d = 0; d < 128; d++) {
                int v = row[d];
                a0 = fmaf(b2f((short)(v & 0xffff)),  wl[slot][2 * d],     a0);
                a1 = fmaf(b2f((short)(v >> 16)),     wl[slot][2 * d + 1], a1);
            }
            out[(size_t)(m0 + pl) * DOUT + slot] = a0 + a1 + out_b[slot];
        }
    }
}

// ---------------------------------------------------------------------------
extern "C" void kernel_launch(void* const* d_in, const int* in_sizes, int n_in,
                              void* d_out, int out_size, void* d_ws, size_t ws_size,
                              hipStream_t stream)
{
    (void)in_sizes; (void)n_in; (void)out_size; (void)ws_size;
    const float* x        = (const float*)d_in[0];
    const float* enc_W    = (const float*)d_in[1];
    const float* enc_b    = (const float*)d_in[2];
    const float* log_dt   = (const float*)d_in[3];
    const float* log_A_re = (const float*)d_in[4];
    const float* A_im     = (const float*)d_in[5];
    const float* C_re     = (const float*)d_in[6];
    const float* C_im     = (const float*)d_in[7];
    const float* Dp       = (const float*)d_in[8];
    const float* Wo       = (const float*)d_in[9];
    const float* bo       = (const float*)d_in[10];
    const float* lnw      = (const float*)d_in[11];
    const float* lnb      = (const float*)d_in[12];
    const float* out_W    = (const float*)d_in[13];
    const float* out_b    = (const float*)d_in[14];
    float* ws = (float*)d_ws;
    __hip_bfloat16* xb  = (__hip_bfloat16*)(ws + OFF_XB);
    __hip_bfloat16* ewb = (__hip_bfloat16*)(ws + OFF_EWB);
    __hip_bfloat16* u   = (__hip_bfloat16*)(ws + OFF_UCM);
    __hip_bfloat16* ycm = (__hip_bfloat16*)(ws + OFF_YCM);
    __hip_bfloat16* mtA = (__hip_bfloat16*)(ws + OFF_MTA);
    __hip_bfloat16* mwA = (__hip_bfloat16*)(ws + OFF_MWA);
    __hip_bfloat16* mvA = (__hip_bfloat16*)(ws + OFF_MVA);
    __hip_bfloat16* wob = (__hip_bfloat16*)(ws + OFF_WOB);

    k_params<<<NL_ * H_ * N2_ / 256, 256, 0, stream>>>(log_dt, log_A_re, A_im, C_re, C_im, ws);
    k_wcvt<<<(NL_ * 2 * H_ * H_ / 4 + 255) / 256, 256, 0, stream>>>(Wo, wob, NL_ * 2 * H_ * H_ / 4);
    k_wcvt<<<(M_ * DIN / 4 + 255) / 256, 256, 0, stream>>>(x, xb, M_ * DIN / 4);
    k_wcvt<<<(H_ * DIN / 4 + 255) / 256, 256, 0, stream>>>(enc_W, ewb, H_ * DIN / 4);
    k_mats_all<<<NL_ * H_, 256, 0, stream>>>(ws, mtA, mwA, mvA);
    k_encoder<<<M_ / 64, 256, 0, stream>>>(xb, ewb, enc_b, u);
    for (int i = 0; i < NL_; i++) {
        k_ssm<<<H_ * B_, 256, 0, stream>>>(u,
            mtA + (size_t)i * H_ * 4096, mwA + (size_t)i * H_ * 4096,
            mvA + (size_t)i * H_ * 4096, ws, i, Dp, ycm);
        k_glu_mfma<<<M_ / 64, 256, 0, stream>>>(ycm,
            wob + (size_t)i * 2 * H_ * H_, bo + (size_t)i * 2 * H_,
            lnw + (size_t)i * H_, lnb + (size_t)i * H_, u);
    }
    k_decoder<<<M_ / 64, 256, 0, stream>>>(u, out_W, out_b, (float*)d_out);
}